// Round 11
// baseline (265.678 us; speedup 1.0000x reference)
//
#include <hip/hip_runtime.h>

typedef __bf16 bf16;
typedef __attribute__((ext_vector_type(4))) __bf16 bf16x4;
typedef __attribute__((ext_vector_type(8))) __bf16 bf16x8;
typedef __attribute__((ext_vector_type(4))) float f32x4;

#define MFMA(A,B,C) __builtin_amdgcn_mfma_f32_16x16x32_bf16(A,B,C,0,0,0)

#define SEQ 2048
#define EMB 512
#define HD  64
#define SCALE 22.627416997969522f  // sqrt(512): scores are divided by E^-0.5
// Online-softmax seed: not -inf (fast-math folds inf constants to poison).
#define NEG_SEED -3.0e4f

// ---------------------------------------------------------------------------
// One-shot fp32 -> bf16 hi/lo conversion (x, W_qkv) and bf16 (W_out).
// Also zeroes the Vs accumulator (gemm_qkv atomicAdds into it).
// ---------------------------------------------------------------------------
__global__ __launch_bounds__(256)
void convert_kernel(const float* __restrict__ x, const float* __restrict__ Wqkv,
                    const float* __restrict__ Wout,
                    bf16* __restrict__ Xh, bf16* __restrict__ Xl,
                    bf16* __restrict__ Wqh, bf16* __restrict__ Wql,
                    bf16* __restrict__ Wo, float* __restrict__ Vs) {
  if (blockIdx.x < 8) Vs[blockIdx.x * 256 + threadIdx.x] = 0.f;  // 32*64 floats
  const int NX = 8192 * 512 / 4;   // f32x4 chunks
  const int NW = 1536 * 512 / 4;
  const int NO = 512 * 512 / 4;
  const int stride = gridDim.x * 256;
  for (int i = blockIdx.x * 256 + threadIdx.x; i < NX + NW + NO; i += stride) {
    const float* src; bf16 *dh, *dl; int j; bool haslo;
    if (i < NX)           { src = x;    dh = Xh;  dl = Xl;  j = i;           haslo = true; }
    else if (i < NX + NW) { src = Wqkv; dh = Wqh; dl = Wql; j = i - NX;      haslo = true; }
    else                  { src = Wout; dh = Wo;  dl = Wo;  j = i - NX - NW; haslo = false; }
    f32x4 v = *(const f32x4*)&src[(size_t)j * 4];
    bf16x4 h4, l4;
#pragma unroll
    for (int r = 0; r < 4; ++r) {
      bf16 h = (bf16)v[r]; h4[r] = h; l4[r] = (bf16)(v[r] - (float)h);
    }
    *(bf16x4*)&dh[(size_t)j * 4] = h4;
    if (haslo) *(bf16x4*)&dl[(size_t)j * 4] = l4;
  }
}

// ---------------------------------------------------------------------------
// QKV projection (round-7 proven form): bf16 hi/lo GEMM, 64x64 tiles,
// XCD-stripe swizzle + XOR-chunk LDS. V-tiles hi-only + fused Vs atomics.
// ---------------------------------------------------------------------------
__global__ __launch_bounds__(256)
void gemm_qkv(const bf16* __restrict__ Xh, const bf16* __restrict__ Xl,
              const bf16* __restrict__ Wh, const bf16* __restrict__ Wl,
              const float* __restrict__ bias,
              bf16* __restrict__ Qh, bf16* __restrict__ Ql,
              bf16* __restrict__ Kh, bf16* __restrict__ Kl,
              bf16* __restrict__ Vrm, float* __restrict__ Vs) {
  __shared__ __align__(16) bf16 Ah[64][64], Al[64][64];
  __shared__ __align__(16) bf16 Bh[64][64], Bl[64][64];
  const int tid  = threadIdx.x;
  const int lane = tid & 63, wave = tid >> 6;
  const int lin = blockIdx.x + gridDim.x * blockIdx.y;
  const int xcd = lin & 7;
  const int w_  = lin >> 3;                  // 0..383
  const int m0 = ((w_ & 15) + xcd * 16) * 64;
  const int n0 = (w_ >> 4) * 64;
  const bool isV = ((n0 % 192) == 128);      // V third: hi-only suffices
  const int wm = (wave >> 1) * 32, wn = (wave & 1) * 32;
  const int c = lane & 15, quad = lane >> 4;
  const int sr   = tid >> 3;                 // 0..31 staging row
  const int scol = (tid & 7) * 8;
  const int sphy = ((tid & 7) ^ (sr & 7)) * 8;   // (sr+32)&7 == sr&7

  const f32x4 zero = {0.f, 0.f, 0.f, 0.f};
  f32x4 acc[2][2];
  acc[0][0] = zero; acc[0][1] = zero; acc[1][0] = zero; acc[1][1] = zero;

  for (int k0 = 0; k0 < 512; k0 += 64) {
    *(bf16x8*)&Ah[sr][sphy]      = *(const bf16x8*)&Xh[(size_t)(m0 + sr     ) * 512 + k0 + scol];
    *(bf16x8*)&Ah[sr + 32][sphy] = *(const bf16x8*)&Xh[(size_t)(m0 + sr + 32) * 512 + k0 + scol];
    *(bf16x8*)&Bh[sr][sphy]      = *(const bf16x8*)&Wh[(size_t)(n0 + sr     ) * 512 + k0 + scol];
    *(bf16x8*)&Bh[sr + 32][sphy] = *(const bf16x8*)&Wh[(size_t)(n0 + sr + 32) * 512 + k0 + scol];
    if (!isV) {
      *(bf16x8*)&Al[sr][sphy]      = *(const bf16x8*)&Xl[(size_t)(m0 + sr     ) * 512 + k0 + scol];
      *(bf16x8*)&Al[sr + 32][sphy] = *(const bf16x8*)&Xl[(size_t)(m0 + sr + 32) * 512 + k0 + scol];
      *(bf16x8*)&Bl[sr][sphy]      = *(const bf16x8*)&Wl[(size_t)(n0 + sr     ) * 512 + k0 + scol];
      *(bf16x8*)&Bl[sr + 32][sphy] = *(const bf16x8*)&Wl[(size_t)(n0 + sr + 32) * 512 + k0 + scol];
    }
    __syncthreads();
#pragma unroll
    for (int ks = 0; ks < 64; ks += 32) {
      const int px = (((ks >> 3) + quad) ^ (c & 7)) * 8;
      bf16x8 ah0 = *(bf16x8*)&Ah[wm + c     ][px];
      bf16x8 ah1 = *(bf16x8*)&Ah[wm + 16 + c][px];
      bf16x8 bh0 = *(bf16x8*)&Bh[wn + c     ][px];
      bf16x8 bh1 = *(bf16x8*)&Bh[wn + 16 + c][px];
      if (isV) {
        acc[0][0] = MFMA(ah0, bh0, acc[0][0]);
        acc[0][1] = MFMA(ah0, bh1, acc[0][1]);
        acc[1][0] = MFMA(ah1, bh0, acc[1][0]);
        acc[1][1] = MFMA(ah1, bh1, acc[1][1]);
      } else {
        bf16x8 al0 = *(bf16x8*)&Al[wm + c     ][px];
        bf16x8 al1 = *(bf16x8*)&Al[wm + 16 + c][px];
        bf16x8 bl0 = *(bf16x8*)&Bl[wn + c     ][px];
        bf16x8 bl1 = *(bf16x8*)&Bl[wn + 16 + c][px];
        acc[0][0] = MFMA(ah0, bh0, acc[0][0]);
        acc[0][0] = MFMA(al0, bh0, acc[0][0]);
        acc[0][0] = MFMA(ah0, bl0, acc[0][0]);
        acc[0][1] = MFMA(ah0, bh1, acc[0][1]);
        acc[0][1] = MFMA(al0, bh1, acc[0][1]);
        acc[0][1] = MFMA(ah0, bl1, acc[0][1]);
        acc[1][0] = MFMA(ah1, bh0, acc[1][0]);
        acc[1][0] = MFMA(al1, bh0, acc[1][0]);
        acc[1][0] = MFMA(ah1, bl0, acc[1][0]);
        acc[1][1] = MFMA(ah1, bh1, acc[1][1]);
        acc[1][1] = MFMA(al1, bh1, acc[1][1]);
        acc[1][1] = MFMA(ah1, bl1, acc[1][1]);
      }
    }
    __syncthreads();
  }

  if (isV) {
#pragma unroll
    for (int nt = 0; nt < 2; ++nt) {
      const int n = n0 + wn + nt * 16 + c;
      const float bv = bias[n];
      const int h = n / 192, d = n % 192 - 128;
      const size_t bh = (size_t)((m0 >> 11) * 8 + h);
      float csum = 0.f;
#pragma unroll
      for (int mt = 0; mt < 2; ++mt)
#pragma unroll
        for (int r = 0; r < 4; ++r) {
          const int m = m0 + wm + mt * 16 + quad * 4 + r;
          const int s = m & 2047;
          float v = acc[mt][nt][r] + bv;
          Vrm[(bh * SEQ + s) * HD + d] = (bf16)v;
          csum += v;
        }
      csum += __shfl_xor(csum, 16, 64);
      csum += __shfl_xor(csum, 32, 64);
      if (quad == 0) atomicAdd(&Vs[bh * HD + d], csum);
    }
  } else {
#pragma unroll
    for (int mt = 0; mt < 2; ++mt) {
#pragma unroll
      for (int nt = 0; nt < 2; ++nt) {
        const int n = n0 + wn + nt * 16 + c;
        const float bv = bias[n];
#pragma unroll
        for (int r = 0; r < 4; ++r) {
          const int m = m0 + wm + mt * 16 + quad * 4 + r;
          float v = acc[mt][nt][r] + bv;
          const int h = n / 192, t = n % 192;
          const size_t bh = (size_t)((m >> 11) * 8 + h);
          const int s = m & 2047;
          if (t < 64) {
            float q = v * SCALE;
            bf16 hi = (bf16)q;
            float lo = q - (float)hi;
            size_t idx = (bh * SEQ + s) * HD + t;
            Qh[idx] = hi; Ql[idx] = (bf16)lo;
          } else {
            bf16 hi = (bf16)v;
            float lo = v - (float)hi;
            size_t idx = (bh * SEQ + s) * HD + (t - 64);
            Kh[idx] = hi; Kl[idx] = (bf16)lo;
          }
        }
      }
    }
  }
}

// ---------------------------------------------------------------------------
// Output projection: bf16 x bf16 (pre-converted Wo), fp32 out. Same XOR-swz.
// ---------------------------------------------------------------------------
__global__ __launch_bounds__(256)
void gemm_out(const bf16* __restrict__ A, const bf16* __restrict__ Wo,
              const float* __restrict__ bias, float* __restrict__ C) {
  __shared__ __align__(16) bf16 As[64][64];
  __shared__ __align__(16) bf16 Bs[64][64];
  const int tid  = threadIdx.x;
  const int lane = tid & 63, wave = tid >> 6;
  const int lin = blockIdx.x + gridDim.x * blockIdx.y;
  const int xcd = lin & 7;
  const int w_  = lin >> 3;                  // 0..127
  const int m0 = ((w_ & 15) + xcd * 16) * 64;
  const int n0 = (w_ >> 4) * 64;
  const int wm = (wave >> 1) * 32, wn = (wave & 1) * 32;
  const int c = lane & 15, quad = lane >> 4;
  const int sr   = tid >> 3;
  const int scol = (tid & 7) * 8;
  const int sphy = ((tid & 7) ^ (sr & 7)) * 8;

  const f32x4 zero = {0.f, 0.f, 0.f, 0.f};
  f32x4 acc[2][2];
  acc[0][0] = zero; acc[0][1] = zero; acc[1][0] = zero; acc[1][1] = zero;

  for (int k0 = 0; k0 < 512; k0 += 64) {
    *(bf16x8*)&As[sr][sphy]      = *(const bf16x8*)&A [(size_t)(m0 + sr     ) * 512 + k0 + scol];
    *(bf16x8*)&As[sr + 32][sphy] = *(const bf16x8*)&A [(size_t)(m0 + sr + 32) * 512 + k0 + scol];
    *(bf16x8*)&Bs[sr][sphy]      = *(const bf16x8*)&Wo[(size_t)(n0 + sr     ) * 512 + k0 + scol];
    *(bf16x8*)&Bs[sr + 32][sphy] = *(const bf16x8*)&Wo[(size_t)(n0 + sr + 32) * 512 + k0 + scol];
    __syncthreads();
#pragma unroll
    for (int ks = 0; ks < 64; ks += 32) {
      const int px = (((ks >> 3) + quad) ^ (c & 7)) * 8;
      bf16x8 a0 = *(bf16x8*)&As[wm + c     ][px];
      bf16x8 a1 = *(bf16x8*)&As[wm + 16 + c][px];
      bf16x8 b0 = *(bf16x8*)&Bs[wn + c     ][px];
      bf16x8 b1 = *(bf16x8*)&Bs[wn + 16 + c][px];
      acc[0][0] = MFMA(a0, b0, acc[0][0]);
      acc[0][1] = MFMA(a0, b1, acc[0][1]);
      acc[1][0] = MFMA(a1, b0, acc[1][0]);
      acc[1][1] = MFMA(a1, b1, acc[1][1]);
    }
    __syncthreads();
  }

#pragma unroll
  for (int mt = 0; mt < 2; ++mt) {
#pragma unroll
    for (int nt = 0; nt < 2; ++nt) {
      const int n = n0 + wn + nt * 16 + c;
      const float bv = bias[n];
#pragma unroll
      for (int r = 0; r < 4; ++r) {
        const int m = m0 + wm + mt * 16 + quad * 4 + r;
        C[(size_t)m * 512 + n] = acc[mt][nt][r] + bv;
      }
    }
  }
}

// ---------------------------------------------------------------------------
// Attention, double softmax, candidate form v2: NO LDS K-staging, NO scan
// barriers. Block = 4 waves = {2 q-tiles} x {2 key-halves}; grid (32,64).
// SCAN: K-fragments loaded DIRECT global->VGPR (lane reads exactly its MFMA
//   fragment; each 128B K-row consumed by 8 lanes; L1/L2-resident; wave
//   pairs share the K stream). 4-tile unroll = 8 independent loads in
//   flight. Running per-query hi-max (primed on tile 0), push packed
//   (f16 score | key idx) into per-(query,half) LDS rings (cap 32).
// FINISH (after the block's single barrier; waves 0-1): true hi-max mrF is
//   now known, so filter ring entries by score > mrF-12 BEFORE any global
//   load -- order statistics leave ~1-3 survivors/query (the flood was junk
//   relative to the final max). Exact fp32 dot, l1 = sum exp, t-1 =
//   exp(p/l1)-1, V-row gather, + Vtot. Same math as round 7 (abs 0.0005).
//   f16 score storage (err ~0.4) + window 12 still covers every key within
//   gap-8 of the true hi-max; ring eviction only drops pre-argmax junk.
// ---------------------------------------------------------------------------
__global__ __launch_bounds__(256)
void attn_kernel(const bf16* __restrict__ Qh, const bf16* __restrict__ Ql,
                 const bf16* __restrict__ Kh, const bf16* __restrict__ Kl,
                 const bf16* __restrict__ Vrm, const float* __restrict__ Vs,
                 bf16* __restrict__ O) {
  __shared__ unsigned int ring[2][2][16][32];   // [qt][khalf][q][slot] 16KB
  __shared__ int   pcnt[2][2][16];
  __shared__ float mrS [2][2][16];
  __shared__ float sS  [2][16][16];             // survivor exact scores
  __shared__ unsigned short sIdx[2][16][16];

  const int tid  = threadIdx.x;
  const int lane = tid & 63, wave = tid >> 6;
  const int c = lane & 15, quad = lane >> 4;
  const int qt = wave & 1, khf = wave >> 1;
  const int bh = blockIdx.x;
  const int q0 = blockIdx.y * 32 + qt * 16;
  const size_t hoff = (size_t)bh * SEQ * HD;
  const bf16* qh_p = Qh + hoff;
  const bf16* kh_p = Kh + hoff;
  const bf16* kl_p = Kl + hoff;
  const bf16* v_p  = Vrm + hoff;
  const f32x4 zero = {0.f, 0.f, 0.f, 0.f};

  bf16x8 qf[2];
#pragma unroll
  for (int t = 0; t < 2; ++t)
    qf[t] = *(const bf16x8*)&qh_p[(size_t)(q0 + c) * HD + t * 32 + quad * 8];

  if (lane < 16) pcnt[qt][khf][lane] = 0;   // own slice, same-wave use

  // lane-fixed K base: key row c of each tile, dims quad*8 (+32 for hi half)
  const bf16* kbase = kh_p + ((size_t)(khf * 1024) + c) * HD + quad * 8;

  // ---- prime running max with tile 0 (no pushes: cold-start suppression) ----
  float mr;
  {
    bf16x8 f0 = *(const bf16x8*)kbase;
    bf16x8 f1 = *(const bf16x8*)(kbase + 32);
    f32x4 sc = MFMA(f0, qf[0], zero);
    sc = MFMA(f1, qf[1], sc);
    float tm = fmaxf(fmaxf(sc[0], sc[1]), fmaxf(sc[2], sc[3]));
    tm = fmaxf(tm, __shfl_xor(tm, 16, 64));
    tm = fmaxf(tm, __shfl_xor(tm, 32, 64));
    mr = tm;
  }

  // ---- dense scan: 64 tiles, 4-tile unroll, direct-global fragments ----
  for (int g4 = 0; g4 < 64; g4 += 4) {
    bf16x8 f[4][2];
#pragma unroll
    for (int t = 0; t < 4; ++t) {
      const bf16* kp = kbase + (size_t)(g4 + t) * (16 * HD);
      f[t][0] = *(const bf16x8*)kp;
      f[t][1] = *(const bf16x8*)(kp + 32);
    }
#pragma unroll
    for (int t = 0; t < 4; ++t) {
      f32x4 sc = MFMA(f[t][0], qf[0], zero);
      sc = MFMA(f[t][1], qf[1], sc);
      const float tm = fmaxf(fmaxf(sc[0], sc[1]), fmaxf(sc[2], sc[3]));
      mr = fmaxf(mr, tm);
      if (tm > mr - 12.f) {
#pragma unroll
        for (int r = 0; r < 4; ++r) {
          if (sc[r] > mr - 12.f) {
            const int slot = atomicAdd(&pcnt[qt][khf][c], 1) & 31;   // ring
            const unsigned short hb =
                __builtin_bit_cast(unsigned short, (_Float16)sc[r]);
            ring[qt][khf][c][slot] = ((unsigned int)hb << 16) |
                (unsigned int)(khf * 1024 + (g4 + t) * 16 + quad * 4 + r);
          }
        }
      }
    }
    mr = fmaxf(mr, __shfl_xor(mr, 16, 64));
    mr = fmaxf(mr, __shfl_xor(mr, 32, 64));
  }
  if (quad == 0) mrS[qt][khf][c] = mr;
  __syncthreads();
  if (wave >= 2) return;   // waves 2-3 done (no further barriers)

  // ---- FINISH: filter rings by final max, exact dot survivors only ----
  const float mrF = fmaxf(mrS[qt][0][c], mrS[qt][1][c]);
  bf16x8 qlf[2];
#pragma unroll
  for (int t = 0; t < 2; ++t)
    qlf[t] = *(const bf16x8*)&Ql[hoff + (size_t)(q0 + c) * HD + t * 32 + quad * 8];
  float qv[16];
#pragma unroll
  for (int j = 0; j < 8; ++j) {
    qv[j]     = (float)qf[0][j] + (float)qlf[0][j];
    qv[8 + j] = (float)qf[1][j] + (float)qlf[1][j];
  }

  int ns = 0;
  float mqC = NEG_SEED;
#pragma unroll
  for (int hh = 0; hh < 2; ++hh) {
    const int n = min(pcnt[qt][hh][c], 32);
    for (int j = 0; j < n; ++j) {
      const unsigned int e = ring[qt][hh][c][j];
      const float sv =
          (float)__builtin_bit_cast(_Float16, (unsigned short)(e >> 16));
      if (sv > mrF - 12.f) {
        const int idx = e & 0xFFFF;
        const size_t kr = (size_t)idx * HD + quad * 8;
        bf16x8 kh0 = *(const bf16x8*)&kh_p[kr];
        bf16x8 kh1 = *(const bf16x8*)&kh_p[kr + 32];
        bf16x8 kl0 = *(const bf16x8*)&kl_p[kr];
        bf16x8 kl1 = *(const bf16x8*)&kl_p[kr + 32];
        float s = 0.f;
#pragma unroll
        for (int jj = 0; jj < 8; ++jj) {
          s = fmaf(qv[jj],     (float)kh0[jj] + (float)kl0[jj], s);
          s = fmaf(qv[8 + jj], (float)kh1[jj] + (float)kl1[jj], s);
        }
        s += __shfl_xor(s, 16, 64);   // partners share c -> uniform branch
        s += __shfl_xor(s, 32, 64);
        if (quad == 0 && ns < 16) { sS[qt][c][ns] = s; sIdx[qt][c][ns] = (unsigned short)idx; }
        mqC = fmaxf(mqC, s);
        ++ns;
      }
    }
  }
  ns = min(ns, 16);

  float l1 = 0.f;
  for (int j = 0; j < ns; ++j) l1 += __expf(sS[qt][c][j] - mqC);
  const float inv1 = 1.f / l1;

  float oc[16];
#pragma unroll
  for (int i = 0; i < 16; ++i) oc[i] = 0.f;
  float l2 = 0.f;
  for (int j = 0; j < ns; ++j) {
    const float a1 = __expf(sS[qt][c][j] - mqC) * inv1;  // attn1 in [0,1]
    const float t1 = __expf(a1) - 1.0f;                  // t-1
    l2 += t1;
    const int idx = sIdx[qt][c][j];
    bf16x8 v0 = *(const bf16x8*)&v_p[(size_t)idx * HD + quad * 8];
    bf16x8 v1 = *(const bf16x8*)&v_p[(size_t)idx * HD + 32 + quad * 8];
#pragma unroll
    for (int jj = 0; jj < 8; ++jj) {
      oc[jj]     += t1 * (float)v0[jj];
      oc[8 + jj] += t1 * (float)v1[jj];
    }
  }

  const int b = bh >> 3, h = bh & 7;
  const float rcp = 1.f / (2048.f + l2);
  const float* vsp = Vs + bh * HD;
  bf16* orow = &O[((size_t)b * SEQ + q0 + c) * EMB + h * HD];
  bf16x8 o0, o1;
#pragma unroll
  for (int jj = 0; jj < 8; ++jj) {
    o0[jj] = (bf16)((oc[jj]     + vsp[quad * 8 + jj])      * rcp);
    o1[jj] = (bf16)((oc[8 + jj] + vsp[32 + quad * 8 + jj]) * rcp);
  }
  *(bf16x8*)&orow[quad * 8]      = o0;
  *(bf16x8*)&orow[32 + quad * 8] = o1;
}

// ---------------------------------------------------------------------------
extern "C" void kernel_launch(void* const* d_in, const int* in_sizes, int n_in,
                              void* d_out, int out_size, void* d_ws, size_t ws_size,
                              hipStream_t stream) {
  const float* x    = (const float*)d_in[0];
  const float* Wqkv = (const float*)d_in[1];
  const float* bqkv = (const float*)d_in[2];
  const float* Wout = (const float*)d_in[3];
  const float* bout = (const float*)d_in[4];
  float* out = (float*)d_out;

  char* ws = (char*)d_ws;
  const size_t SZ = (size_t)32 * SEQ * HD * 2;  // 8 MiB per array
  bf16* Qh  = (bf16*)(ws + 0 * SZ);
  bf16* Ql  = (bf16*)(ws + 1 * SZ);
  bf16* Kh  = (bf16*)(ws + 2 * SZ);
  bf16* Kl  = (bf16*)(ws + 3 * SZ);
  bf16* Vrm = (bf16*)(ws + 4 * SZ);
  bf16* XhO = (bf16*)(ws + 5 * SZ);  // Xh during proj; overwritten by O
  bf16* Xl  = (bf16*)(ws + 6 * SZ);
  bf16* Wqh = (bf16*)(ws + 7 * SZ);
  bf16* Wql = (bf16*)(ws + 7 * SZ + 0x180000);
  bf16* Wo  = (bf16*)(ws + 7 * SZ + 0x300000);
  float* Vs = (float*)(ws + 7 * SZ + 0x380000);  // 32x64 f32 Vtot (atomics)

  convert_kernel<<<dim3(2048), 256, 0, stream>>>(x, Wqkv, Wout, XhO, Xl, Wqh, Wql, Wo, Vs);
  gemm_qkv<<<dim3(128, 24), 256, 0, stream>>>(XhO, Xl, Wqh, Wql, bqkv, Qh, Ql, Kh, Kl, Vrm, Vs);
  attn_kernel<<<dim3(32, 64), 256, 0, stream>>>(Qh, Ql, Kh, Kl, Vrm, Vs, XhO);
  gemm_out<<<dim3(128, 8), 256, 0, stream>>>(XhO, Wo, bout, out);
}

// Round 12
// 195.368 us; speedup vs baseline: 1.3599x; 1.3599x over previous
//
#include <hip/hip_runtime.h>

typedef __bf16 bf16;
typedef __attribute__((ext_vector_type(4))) __bf16 bf16x4;
typedef __attribute__((ext_vector_type(8))) __bf16 bf16x8;
typedef __attribute__((ext_vector_type(4))) float f32x4;

#define MFMA(A,B,C) __builtin_amdgcn_mfma_f32_16x16x32_bf16(A,B,C,0,0,0)

#define SEQ 2048
#define EMB 512
#define HD  64
#define SCALE 22.627416997969522f  // sqrt(512): scores are divided by E^-0.5
// Online-softmax seed: not -inf (fast-math folds inf constants to poison).
#define NEG_SEED -3.0e4f
#define LCAP 24                    // per-query candidate ring capacity

// Async global->LDS 16B copy: wave-uniform LDS base + lane*16 dest, per-lane
// global src. Drained by the vmcnt(0) the compiler emits before s_barrier.
__device__ __forceinline__ void gld16(const bf16* g, bf16* l) {
  __builtin_amdgcn_global_load_lds(
      (const __attribute__((address_space(1))) void*)g,
      (__attribute__((address_space(3))) void*)l, 16, 0, 0);
}

// ---------------------------------------------------------------------------
// One-shot fp32 -> bf16 hi/lo conversion (x, W_qkv) and bf16 (W_out).
// Also zeroes the Vs accumulator (gemm_qkv atomicAdds into it).
// ---------------------------------------------------------------------------
__global__ __launch_bounds__(256)
void convert_kernel(const float* __restrict__ x, const float* __restrict__ Wqkv,
                    const float* __restrict__ Wout,
                    bf16* __restrict__ Xh, bf16* __restrict__ Xl,
                    bf16* __restrict__ Wqh, bf16* __restrict__ Wql,
                    bf16* __restrict__ Wo, float* __restrict__ Vs) {
  if (blockIdx.x < 8) Vs[blockIdx.x * 256 + threadIdx.x] = 0.f;  // 32*64 floats
  const int NX = 8192 * 512 / 4;   // f32x4 chunks
  const int NW = 1536 * 512 / 4;
  const int NO = 512 * 512 / 4;
  const int stride = gridDim.x * 256;
  for (int i = blockIdx.x * 256 + threadIdx.x; i < NX + NW + NO; i += stride) {
    const float* src; bf16 *dh, *dl; int j; bool haslo;
    if (i < NX)           { src = x;    dh = Xh;  dl = Xl;  j = i;           haslo = true; }
    else if (i < NX + NW) { src = Wqkv; dh = Wqh; dl = Wql; j = i - NX;      haslo = true; }
    else                  { src = Wout; dh = Wo;  dl = Wo;  j = i - NX - NW; haslo = false; }
    f32x4 v = *(const f32x4*)&src[(size_t)j * 4];
    bf16x4 h4, l4;
#pragma unroll
    for (int r = 0; r < 4; ++r) {
      bf16 h = (bf16)v[r]; h4[r] = h; l4[r] = (bf16)(v[r] - (float)h);
    }
    *(bf16x4*)&dh[(size_t)j * 4] = h4;
    if (haslo) *(bf16x4*)&dl[(size_t)j * 4] = l4;
  }
}

// ---------------------------------------------------------------------------
// QKV projection: bf16 hi/lo GEMM, 64x64 tiles, XCD-stripe swizzle.
// Staging via global_load_lds(16B): linear LDS dest, PRE-SWIZZLED global
// source (lane l loads col ((l&7)^(l>>3))*8) -> identical XOR-chunk layout,
// bit-identical results to the reg-staged version. V-tiles hi-only + fused
// Vs atomics.
// ---------------------------------------------------------------------------
__global__ __launch_bounds__(256)
void gemm_qkv(const bf16* __restrict__ Xh, const bf16* __restrict__ Xl,
              const bf16* __restrict__ Wh, const bf16* __restrict__ Wl,
              const float* __restrict__ bias,
              bf16* __restrict__ Qh, bf16* __restrict__ Ql,
              bf16* __restrict__ Kh, bf16* __restrict__ Kl,
              bf16* __restrict__ Vrm, float* __restrict__ Vs) {
  __shared__ __align__(16) bf16 Ah[64][64], Al[64][64];
  __shared__ __align__(16) bf16 Bh[64][64], Bl[64][64];
  const int tid  = threadIdx.x;
  const int lane = tid & 63, wave = tid >> 6;
  const int lin = blockIdx.x + gridDim.x * blockIdx.y;
  const int xcd = lin & 7;
  const int w_  = lin >> 3;                  // 0..383
  const int m0 = ((w_ & 15) + xcd * 16) * 64;
  const int n0 = (w_ >> 4) * 64;
  const bool isV = ((n0 % 192) == 128);      // V third: hi-only suffices
  const int wm = (wave >> 1) * 32, wn = (wave & 1) * 32;
  const int c = lane & 15, quad = lane >> 4;

  // staging geometry: wave w, round j covers LDS rows j*32 + w*8 .. +8
  const int g_row = wave * 8 + (lane >> 3);               // row&7 == lane>>3
  const int g_col = ((lane & 7) ^ (lane >> 3)) * 8;       // pre-swizzled col
  const bf16* pA0 = Xh + (size_t)(m0 + g_row)      * 512 + g_col;
  const bf16* pA1 = Xh + (size_t)(m0 + 32 + g_row) * 512 + g_col;
  const bf16* pB0 = Wh + (size_t)(n0 + g_row)      * 512 + g_col;
  const bf16* pB1 = Wh + (size_t)(n0 + 32 + g_row) * 512 + g_col;
  const bf16* pAl0 = Xl + (size_t)(m0 + g_row)      * 512 + g_col;
  const bf16* pAl1 = Xl + (size_t)(m0 + 32 + g_row) * 512 + g_col;
  const bf16* pBl0 = Wl + (size_t)(n0 + g_row)      * 512 + g_col;
  const bf16* pBl1 = Wl + (size_t)(n0 + 32 + g_row) * 512 + g_col;
  bf16* lA0 = &Ah[wave * 8][0];      bf16* lA1 = &Ah[32 + wave * 8][0];
  bf16* lB0 = &Bh[wave * 8][0];      bf16* lB1 = &Bh[32 + wave * 8][0];
  bf16* lAl0 = &Al[wave * 8][0];     bf16* lAl1 = &Al[32 + wave * 8][0];
  bf16* lBl0 = &Bl[wave * 8][0];     bf16* lBl1 = &Bl[32 + wave * 8][0];

  const f32x4 zero = {0.f, 0.f, 0.f, 0.f};
  f32x4 acc[2][2];
  acc[0][0] = zero; acc[0][1] = zero; acc[1][0] = zero; acc[1][1] = zero;

  for (int k0 = 0; k0 < 512; k0 += 64) {
    gld16(pA0 + k0, lA0); gld16(pA1 + k0, lA1);
    gld16(pB0 + k0, lB0); gld16(pB1 + k0, lB1);
    if (!isV) {
      gld16(pAl0 + k0, lAl0); gld16(pAl1 + k0, lAl1);
      gld16(pBl0 + k0, lBl0); gld16(pBl1 + k0, lBl1);
    }
    __syncthreads();
#pragma unroll
    for (int ks = 0; ks < 64; ks += 32) {
      const int px = (((ks >> 3) + quad) ^ (c & 7)) * 8;
      bf16x8 ah0 = *(bf16x8*)&Ah[wm + c     ][px];
      bf16x8 ah1 = *(bf16x8*)&Ah[wm + 16 + c][px];
      bf16x8 bh0 = *(bf16x8*)&Bh[wn + c     ][px];
      bf16x8 bh1 = *(bf16x8*)&Bh[wn + 16 + c][px];
      if (isV) {
        acc[0][0] = MFMA(ah0, bh0, acc[0][0]);
        acc[0][1] = MFMA(ah0, bh1, acc[0][1]);
        acc[1][0] = MFMA(ah1, bh0, acc[1][0]);
        acc[1][1] = MFMA(ah1, bh1, acc[1][1]);
      } else {
        bf16x8 al0 = *(bf16x8*)&Al[wm + c     ][px];
        bf16x8 al1 = *(bf16x8*)&Al[wm + 16 + c][px];
        bf16x8 bl0 = *(bf16x8*)&Bl[wn + c     ][px];
        bf16x8 bl1 = *(bf16x8*)&Bl[wn + 16 + c][px];
        acc[0][0] = MFMA(ah0, bh0, acc[0][0]);
        acc[0][0] = MFMA(al0, bh0, acc[0][0]);
        acc[0][0] = MFMA(ah0, bl0, acc[0][0]);
        acc[0][1] = MFMA(ah0, bh1, acc[0][1]);
        acc[0][1] = MFMA(al0, bh1, acc[0][1]);
        acc[0][1] = MFMA(ah0, bl1, acc[0][1]);
        acc[1][0] = MFMA(ah1, bh0, acc[1][0]);
        acc[1][0] = MFMA(al1, bh0, acc[1][0]);
        acc[1][0] = MFMA(ah1, bl0, acc[1][0]);
        acc[1][1] = MFMA(ah1, bh1, acc[1][1]);
        acc[1][1] = MFMA(al1, bh1, acc[1][1]);
        acc[1][1] = MFMA(ah1, bl1, acc[1][1]);
      }
    }
    __syncthreads();
  }

  if (isV) {
#pragma unroll
    for (int nt = 0; nt < 2; ++nt) {
      const int n = n0 + wn + nt * 16 + c;
      const float bv = bias[n];
      const int h = n / 192, d = n % 192 - 128;
      const size_t bh = (size_t)((m0 >> 11) * 8 + h);
      float csum = 0.f;
#pragma unroll
      for (int mt = 0; mt < 2; ++mt)
#pragma unroll
        for (int r = 0; r < 4; ++r) {
          const int m = m0 + wm + mt * 16 + quad * 4 + r;
          const int s = m & 2047;
          float v = acc[mt][nt][r] + bv;
          Vrm[(bh * SEQ + s) * HD + d] = (bf16)v;
          csum += v;
        }
      csum += __shfl_xor(csum, 16, 64);
      csum += __shfl_xor(csum, 32, 64);
      if (quad == 0) atomicAdd(&Vs[bh * HD + d], csum);
    }
  } else {
#pragma unroll
    for (int mt = 0; mt < 2; ++mt) {
#pragma unroll
      for (int nt = 0; nt < 2; ++nt) {
        const int n = n0 + wn + nt * 16 + c;
        const float bv = bias[n];
#pragma unroll
        for (int r = 0; r < 4; ++r) {
          const int m = m0 + wm + mt * 16 + quad * 4 + r;
          float v = acc[mt][nt][r] + bv;
          const int h = n / 192, t = n % 192;
          const size_t bh = (size_t)((m >> 11) * 8 + h);
          const int s = m & 2047;
          if (t < 64) {
            float q = v * SCALE;
            bf16 hi = (bf16)q;
            float lo = q - (float)hi;
            size_t idx = (bh * SEQ + s) * HD + t;
            Qh[idx] = hi; Ql[idx] = (bf16)lo;
          } else {
            bf16 hi = (bf16)v;
            float lo = v - (float)hi;
            size_t idx = (bh * SEQ + s) * HD + (t - 64);
            Kh[idx] = hi; Kl[idx] = (bf16)lo;
          }
        }
      }
    }
  }
}

// ---------------------------------------------------------------------------
// Output projection: bf16 x bf16, fp32 out. Same global_load_lds staging.
// ---------------------------------------------------------------------------
__global__ __launch_bounds__(256)
void gemm_out(const bf16* __restrict__ A, const bf16* __restrict__ Wo,
              const float* __restrict__ bias, float* __restrict__ C) {
  __shared__ __align__(16) bf16 As[64][64];
  __shared__ __align__(16) bf16 Bs[64][64];
  const int tid  = threadIdx.x;
  const int lane = tid & 63, wave = tid >> 6;
  const int lin = blockIdx.x + gridDim.x * blockIdx.y;
  const int xcd = lin & 7;
  const int w_  = lin >> 3;                  // 0..127
  const int m0 = ((w_ & 15) + xcd * 16) * 64;
  const int n0 = (w_ >> 4) * 64;
  const int wm = (wave >> 1) * 32, wn = (wave & 1) * 32;
  const int c = lane & 15, quad = lane >> 4;

  const int g_row = wave * 8 + (lane >> 3);
  const int g_col = ((lane & 7) ^ (lane >> 3)) * 8;
  const bf16* pA0 = A  + (size_t)(m0 + g_row)      * 512 + g_col;
  const bf16* pA1 = A  + (size_t)(m0 + 32 + g_row) * 512 + g_col;
  const bf16* pB0 = Wo + (size_t)(n0 + g_row)      * 512 + g_col;
  const bf16* pB1 = Wo + (size_t)(n0 + 32 + g_row) * 512 + g_col;
  bf16* lA0 = &As[wave * 8][0];  bf16* lA1 = &As[32 + wave * 8][0];
  bf16* lB0 = &Bs[wave * 8][0];  bf16* lB1 = &Bs[32 + wave * 8][0];

  const f32x4 zero = {0.f, 0.f, 0.f, 0.f};
  f32x4 acc[2][2];
  acc[0][0] = zero; acc[0][1] = zero; acc[1][0] = zero; acc[1][1] = zero;

  for (int k0 = 0; k0 < 512; k0 += 64) {
    gld16(pA0 + k0, lA0); gld16(pA1 + k0, lA1);
    gld16(pB0 + k0, lB0); gld16(pB1 + k0, lB1);
    __syncthreads();
#pragma unroll
    for (int ks = 0; ks < 64; ks += 32) {
      const int px = (((ks >> 3) + quad) ^ (c & 7)) * 8;
      bf16x8 a0 = *(bf16x8*)&As[wm + c     ][px];
      bf16x8 a1 = *(bf16x8*)&As[wm + 16 + c][px];
      bf16x8 b0 = *(bf16x8*)&Bs[wn + c     ][px];
      bf16x8 b1 = *(bf16x8*)&Bs[wn + 16 + c][px];
      acc[0][0] = MFMA(a0, b0, acc[0][0]);
      acc[0][1] = MFMA(a0, b1, acc[0][1]);
      acc[1][0] = MFMA(a1, b0, acc[1][0]);
      acc[1][1] = MFMA(a1, b1, acc[1][1]);
    }
    __syncthreads();
  }

#pragma unroll
  for (int mt = 0; mt < 2; ++mt) {
#pragma unroll
    for (int nt = 0; nt < 2; ++nt) {
      const int n = n0 + wn + nt * 16 + c;
      const float bv = bias[n];
#pragma unroll
      for (int r = 0; r < 4; ++r) {
        const int m = m0 + wm + mt * 16 + quad * 4 + r;
        C[(size_t)m * 512 + n] = acc[mt][nt][r] + bv;
      }
    }
  }
}

// ---------------------------------------------------------------------------
// Attention (round-7 proven candidate-index form; staging via
// global_load_lds with pre-swizzled source -> bit-identical).
// SCAN: dense staged hi-only, 2 MFMA/tile, running per-query max, window-12
//   index pushes into per-query rings (cap 24). No exp/l1/kl in the loop.
// FINISH: exact fp32 VALU dot for listed keys, exact max, l1 = sum exp,
//   t-1 = exp(p/l1)-1, V-row gather, + Vtot.
// ---------------------------------------------------------------------------
__global__ __launch_bounds__(256, 4)
void attn_kernel(const bf16* __restrict__ Qh, const bf16* __restrict__ Ql,
                 const bf16* __restrict__ Kh, const bf16* __restrict__ Kl,
                 const bf16* __restrict__ Vrm, const float* __restrict__ Vs,
                 bf16* __restrict__ O) {
  __shared__ __align__(16) bf16 SK[2][64][64];        // 16KB Kh stage
  __shared__ float sS[4][16][LCAP];                    // exact-s scratch
  __shared__ unsigned short sI[4][16][LCAP];           // candidate key idx
  __shared__ int pcnt[4][16];

  const int tid  = threadIdx.x;
  const int lane = tid & 63, wave = tid >> 6;
  const int c = lane & 15, quad = lane >> 4;
  const int bh = blockIdx.x;
  const int q0 = blockIdx.y * 64 + wave * 16;
  const size_t hoff = (size_t)bh * SEQ * HD;
  const bf16* qh_p = Qh + hoff;
  const bf16* ql_p = Ql + hoff;
  const bf16* kh_p = Kh + hoff;
  const bf16* kl_p = Kl + hoff;
  const bf16* v_p  = Vrm + hoff;
  const f32x4 zero = {0.f, 0.f, 0.f, 0.f};

  const int pc0  = ((0 + quad) ^ (c & 7)) * 8;
  const int pc1  = ((4 + quad) ^ (c & 7)) * 8;

  // staging geometry (pre-swizzled source, linear LDS dest)
  const int g_row = wave * 8 + (lane >> 3);
  const int g_col = ((lane & 7) ^ (lane >> 3)) * 8;
  const bf16* kst0 = kh_p + (size_t)g_row        * HD + g_col;
  const bf16* kst1 = kh_p + (size_t)(32 + g_row) * HD + g_col;

  bf16x8 qf[2];
#pragma unroll
  for (int t = 0; t < 2; ++t)
    qf[t] = *(const bf16x8*)&qh_p[(size_t)(q0 + c) * HD + t * 32 + quad * 8];
  if (lane < 16) pcnt[wave][lane] = 0;   // same-wave use only

  // ================= SCAN: dense hi-only, index collection =================
  gld16(kst0, &SK[0][wave * 8][0]);
  gld16(kst1, &SK[0][32 + wave * 8][0]);
  __syncthreads();

  float mr = NEG_SEED;
  int buf = 0;
  for (int cs = 0; cs < 32; ++cs) {
    if (cs < 31) {
      const size_t adv = (size_t)(cs + 1) * 64 * HD;
      gld16(kst0 + adv, &SK[buf ^ 1][wave * 8][0]);
      gld16(kst1 + adv, &SK[buf ^ 1][32 + wave * 8][0]);
    }
#pragma unroll
    for (int t = 0; t < 4; ++t) {
      const int g = cs * 4 + t;
      bf16x8 kh0 = *(bf16x8*)&SK[buf][t * 16 + c][pc0];
      bf16x8 kh1 = *(bf16x8*)&SK[buf][t * 16 + c][pc1];
      f32x4 sc = MFMA(kh0, qf[0], zero);
      sc = MFMA(kh1, qf[1], sc);
      const float tm = fmaxf(fmaxf(sc[0], sc[1]), fmaxf(sc[2], sc[3]));
      mr = fmaxf(mr, tm);
      if (t & 1) {   // quad-share the running max every 2 tiles
        mr = fmaxf(mr, __shfl_xor(mr, 16, 64));
        mr = fmaxf(mr, __shfl_xor(mr, 32, 64));
      }
      if (tm > mr - 12.f) {
#pragma unroll
        for (int r = 0; r < 4; ++r) {
          if (sc[r] > mr - 12.f) {
            const int slot = atomicAdd(&pcnt[wave][c], 1) % LCAP;  // ring
            sI[wave][c][slot] = (unsigned short)(g * 16 + quad * 4 + r);
          }
        }
      }
    }
    if (cs < 31) {
      __syncthreads();
      buf ^= 1;
    }
  }

  // ================= FINISH: exact, per-quad, barrier-free =================
  bf16x8 qlf[2];
#pragma unroll
  for (int t = 0; t < 2; ++t)
    qlf[t] = *(const bf16x8*)&ql_p[(size_t)(q0 + c) * HD + t * 32 + quad * 8];
  float qv[16];
#pragma unroll
  for (int j = 0; j < 8; ++j) {
    qv[j]     = (float)qf[0][j] + (float)qlf[0][j];
    qv[8 + j] = (float)qf[1][j] + (float)qlf[1][j];
  }
  const int n = min(pcnt[wave][c], LCAP);
  float mqC = NEG_SEED;
  for (int j = 0; j < n; ++j) {
    const int idx = sI[wave][c][j];
    const size_t kr = (size_t)idx * HD + quad * 8;
    bf16x8 kh0 = *(const bf16x8*)&kh_p[kr];
    bf16x8 kh1 = *(const bf16x8*)&kh_p[kr + 32];
    bf16x8 kl0 = *(const bf16x8*)&kl_p[kr];
    bf16x8 kl1 = *(const bf16x8*)&kl_p[kr + 32];
    float s = 0.f;
#pragma unroll
    for (int jj = 0; jj < 8; ++jj) {
      s = fmaf(qv[jj],     (float)kh0[jj] + (float)kl0[jj], s);
      s = fmaf(qv[8 + jj], (float)kh1[jj] + (float)kl1[jj], s);
    }
    s += __shfl_xor(s, 16, 64);
    s += __shfl_xor(s, 32, 64);
    if (quad == 0) sS[wave][c][j] = s;
    mqC = fmaxf(mqC, s);
  }
  float l1 = 0.f;
  for (int j = 0; j < n; ++j) l1 += __expf(sS[wave][c][j] - mqC);
  const float inv1 = 1.f / l1;

  float oc[16];
#pragma unroll
  for (int i = 0; i < 16; ++i) oc[i] = 0.f;
  float l2 = 0.f;
  for (int j = 0; j < n; ++j) {
    const float a1 = __expf(sS[wave][c][j] - mqC) * inv1;  // attn1 in [0,1]
    const float t1 = __expf(a1) - 1.0f;                    // t-1
    l2 += t1;
    const int idx = sI[wave][c][j];
    bf16x8 v0 = *(const bf16x8*)&v_p[(size_t)idx * HD + quad * 8];
    bf16x8 v1 = *(const bf16x8*)&v_p[(size_t)idx * HD + 32 + quad * 8];
#pragma unroll
    for (int jj = 0; jj < 8; ++jj) {
      oc[jj]     += t1 * (float)v0[jj];
      oc[8 + jj] += t1 * (float)v1[jj];
    }
  }

  const int b = bh >> 3, h = bh & 7;
  const float rcp = 1.f / (2048.f + l2);
  const float* vsp = Vs + bh * HD;
  bf16* orow = &O[((size_t)b * SEQ + q0 + c) * EMB + h * HD];
  bf16x8 o0, o1;
#pragma unroll
  for (int jj = 0; jj < 8; ++jj) {
    o0[jj] = (bf16)((oc[jj]     + vsp[quad * 8 + jj])      * rcp);
    o1[jj] = (bf16)((oc[8 + jj] + vsp[32 + quad * 8 + jj]) * rcp);
  }
  *(bf16x8*)&orow[quad * 8]      = o0;
  *(bf16x8*)&orow[32 + quad * 8] = o1;
}

// ---------------------------------------------------------------------------
extern "C" void kernel_launch(void* const* d_in, const int* in_sizes, int n_in,
                              void* d_out, int out_size, void* d_ws, size_t ws_size,
                              hipStream_t stream) {
  const float* x    = (const float*)d_in[0];
  const float* Wqkv = (const float*)d_in[1];
  const float* bqkv = (const float*)d_in[2];
  const float* Wout = (const float*)d_in[3];
  const float* bout = (const float*)d_in[4];
  float* out = (float*)d_out;

  char* ws = (char*)d_ws;
  const size_t SZ = (size_t)32 * SEQ * HD * 2;  // 8 MiB per array
  bf16* Qh  = (bf16*)(ws + 0 * SZ);
  bf16* Ql  = (bf16*)(ws + 1 * SZ);
  bf16* Kh  = (bf16*)(ws + 2 * SZ);
  bf16* Kl  = (bf16*)(ws + 3 * SZ);
  bf16* Vrm = (bf16*)(ws + 4 * SZ);
  bf16* XhO = (bf16*)(ws + 5 * SZ);  // Xh during proj; overwritten by O
  bf16* Xl  = (bf16*)(ws + 6 * SZ);
  bf16* Wqh = (bf16*)(ws + 7 * SZ);
  bf16* Wql = (bf16*)(ws + 7 * SZ + 0x180000);
  bf16* Wo  = (bf16*)(ws + 7 * SZ + 0x300000);
  float* Vs = (float*)(ws + 7 * SZ + 0x380000);  // 32x64 f32 Vtot (atomics)

  convert_kernel<<<dim3(2048), 256, 0, stream>>>(x, Wqkv, Wout, XhO, Xl, Wqh, Wql, Wo, Vs);
  gemm_qkv<<<dim3(128, 24), 256, 0, stream>>>(XhO, Xl, Wqh, Wql, bqkv, Qh, Ql, Kh, Kl, Vrm, Vs);
  attn_kernel<<<dim3(32, 32), 256, 0, stream>>>(Qh, Ql, Kh, Kl, Vrm, Vs, XhO);
  gemm_out<<<dim3(128, 8), 256, 0, stream>>>(XhO, Wo, bout, out);
}